// Round 1
// baseline (17.726 us; speedup 1.0000x reference)
//
#include <hip/hip_runtime.h>

// H1 arm forward kinematics, elementwise over B = 2097152.
// out[i] = offset + (-U - F*ce)*col3(R_sh) + (-F*se)*col1(R_sh)
// col3(R_sh) = [sp*cr, -sr, cp*cr]          (yaw drops out)
// col1(R_sh) = [cp*cy + sp*sr*sy, cr*sy, -sp*cy + cp*sr*sy]

#define KTORSO_H    0.42999f
#define KSHOULDER_W 0.3107f
#define KUPPER_ARM  0.19886f
#define KFOREARM    0.3f

__device__ __forceinline__ void kin1(float pitch, float roll, float yaw, float elbow,
                                     float& ox, float& oy, float& oz) {
    float sp, cp, sr, cr, sy, cy, se, ce;
    __sincosf(pitch, &sp, &cp);
    __sincosf(roll,  &sr, &cr);
    __sincosf(yaw,   &sy, &cy);
    __sincosf(elbow, &se, &ce);

    float a1x = cp * cy + sp * sr * sy;
    float a1y = cr * sy;
    float a1z = -sp * cy + cp * sr * sy;

    float a3x = sp * cr;
    float a3y = -sr;
    float a3z = cp * cr;

    float k3 = -KUPPER_ARM - KFOREARM * ce;   // coefficient on col3
    float k1 = -KFOREARM * se;                // coefficient on col1

    ox = k3 * a3x + k1 * a1x;                 // offset.x = 0
    oy = KSHOULDER_W + k3 * a3y + k1 * a1y;
    oz = KTORSO_H    + k3 * a3z + k1 * a1z;
}

__global__ __launch_bounds__(256) void h1_kin_kernel(
    const float4* __restrict__ qp4,
    const float4* __restrict__ qr4,
    const float4* __restrict__ qy4,
    const float4* __restrict__ qe4,
    float4* __restrict__ out4,
    int n4)  // n4 = B/4
{
    int i = blockIdx.x * blockDim.x + threadIdx.x;
    if (i >= n4) return;

    float4 p = qp4[i];
    float4 r = qr4[i];
    float4 y = qy4[i];
    float4 e = qe4[i];

    float o[12];
    kin1(p.x, r.x, y.x, e.x, o[0], o[1], o[2]);
    kin1(p.y, r.y, y.y, e.y, o[3], o[4], o[5]);
    kin1(p.z, r.z, y.z, e.z, o[6], o[7], o[8]);
    kin1(p.w, r.w, y.w, e.w, o[9], o[10], o[11]);

    // 12 contiguous floats per thread -> 3 float4 stores
    float4 v0 = make_float4(o[0], o[1], o[2], o[3]);
    float4 v1 = make_float4(o[4], o[5], o[6], o[7]);
    float4 v2 = make_float4(o[8], o[9], o[10], o[11]);
    long base = (long)i * 3;
    out4[base + 0] = v0;
    out4[base + 1] = v1;
    out4[base + 2] = v2;
}

extern "C" void kernel_launch(void* const* d_in, const int* in_sizes, int n_in,
                              void* d_out, int out_size, void* d_ws, size_t ws_size,
                              hipStream_t stream) {
    const float* qp = (const float*)d_in[0];
    const float* qr = (const float*)d_in[1];
    const float* qy = (const float*)d_in[2];
    const float* qe = (const float*)d_in[3];
    float* out = (float*)d_out;

    int n = in_sizes[0];        // B = 2097152 (divisible by 4)
    int n4 = n / 4;
    int block = 256;
    int grid = (n4 + block - 1) / block;   // 2048

    h1_kin_kernel<<<grid, block, 0, stream>>>(
        (const float4*)qp, (const float4*)qr, (const float4*)qy, (const float4*)qe,
        (float4*)out, n4);
}

// Round 2
// 14.484 us; speedup vs baseline: 1.2238x; 1.2238x over previous
//
#include <hip/hip_runtime.h>

// H1 arm forward kinematics, elementwise over B = 2097152.
// out[i] = offset + (-U - F*ce)*col3(R_sh) + (-F*se)*col1(R_sh)
// col3(R_sh) = [sp*cr, -sr, cp*cr]          (yaw drops out of the elbow term)
// col1(R_sh) = [cp*cy + sp*sr*sy, cr*sy, -sp*cy + cp*sr*sy]
//
// R1: stores were 3x float4 per thread at 48B lane-stride (uncoalesced).
// Now stage 12 floats/thread in LDS, then write wave-contiguous float4s.

#define KTORSO_H    0.42999f
#define KSHOULDER_W 0.3107f
#define KUPPER_ARM  0.19886f
#define KFOREARM    0.3f

__device__ __forceinline__ void kin1(float pitch, float roll, float yaw, float elbow,
                                     float& ox, float& oy, float& oz) {
    float sp, cp, sr, cr, sy, cy, se, ce;
    __sincosf(pitch, &sp, &cp);
    __sincosf(roll,  &sr, &cr);
    __sincosf(yaw,   &sy, &cy);
    __sincosf(elbow, &se, &ce);

    float a1x = cp * cy + sp * sr * sy;
    float a1y = cr * sy;
    float a1z = -sp * cy + cp * sr * sy;

    float a3x = sp * cr;
    float a3y = -sr;
    float a3z = cp * cr;

    float k3 = -KUPPER_ARM - KFOREARM * ce;   // coefficient on col3
    float k1 = -KFOREARM * se;                // coefficient on col1

    ox = k3 * a3x + k1 * a1x;                 // offset.x = 0
    oy = KSHOULDER_W + k3 * a3y + k1 * a1y;
    oz = KTORSO_H    + k3 * a3z + k1 * a1z;
}

__global__ __launch_bounds__(256) void h1_kin_kernel(
    const float4* __restrict__ qp4,
    const float4* __restrict__ qr4,
    const float4* __restrict__ qy4,
    const float4* __restrict__ qe4,
    float4* __restrict__ out4,
    int n4)  // n4 = B/4
{
    __shared__ float4 lds4[768];   // 256 threads * 3 float4 = 12 KB

    int t = threadIdx.x;
    int i = blockIdx.x * 256 + t;
    if (i >= n4) return;           // grid divides exactly; kept for safety

    float4 p = qp4[i];
    float4 r = qr4[i];
    float4 y = qy4[i];
    float4 e = qe4[i];

    float o[12];
    kin1(p.x, r.x, y.x, e.x, o[0], o[1], o[2]);
    kin1(p.y, r.y, y.y, e.y, o[3], o[4], o[5]);
    kin1(p.z, r.z, y.z, e.z, o[6], o[7], o[8]);
    kin1(p.w, r.w, y.w, e.w, o[9], o[10], o[11]);

    // Stage: thread t owns lds4[t*3 .. t*3+2] (48B lane-stride covers all 32
    // banks per 8 lanes -> minimum aliasing for b128 writes).
    lds4[t * 3 + 0] = make_float4(o[0], o[1], o[2], o[3]);
    lds4[t * 3 + 1] = make_float4(o[4], o[5], o[6], o[7]);
    lds4[t * 3 + 2] = make_float4(o[8], o[9], o[10], o[11]);

    __syncthreads();

    // Coalesced store: lane t writes float4 #(k*256+t) of this block's
    // 768-float4 output span -> 1024B contiguous per wave instruction.
    long base = (long)blockIdx.x * 768;
    #pragma unroll
    for (int k = 0; k < 3; ++k) {
        out4[base + k * 256 + t] = lds4[k * 256 + t];
    }
}

extern "C" void kernel_launch(void* const* d_in, const int* in_sizes, int n_in,
                              void* d_out, int out_size, void* d_ws, size_t ws_size,
                              hipStream_t stream) {
    const float* qp = (const float*)d_in[0];
    const float* qr = (const float*)d_in[1];
    const float* qy = (const float*)d_in[2];
    const float* qe = (const float*)d_in[3];
    float* out = (float*)d_out;

    int n = in_sizes[0];        // B = 2097152 (divisible by 4)
    int n4 = n / 4;
    int block = 256;
    int grid = (n4 + block - 1) / block;   // 2048

    h1_kin_kernel<<<grid, block, 0, stream>>>(
        (const float4*)qp, (const float4*)qr, (const float4*)qy, (const float4*)qe,
        (float4*)out, n4);
}

// Round 4
// 11.754 us; speedup vs baseline: 1.5081x; 1.2323x over previous
//
#include <hip/hip_runtime.h>

// H1 arm forward kinematics, elementwise over B = 2097152.
// out[i] = offset + (-U - F*ce)*col3(R_sh) + (-F*se)*col1(R_sh)
// col3(R_sh) = [sp*cr, -sr, cp*cr]          (yaw drops out of the elbow term)
// col1(R_sh) = [cp*cy + sp*sr*sy, cr*sy, -sp*cy + cp*sr*sy]
//
// R2: LDS store-transpose, 4 elem/thread -> 14.5 us.
// R4: 8 elem/thread, 1 barrier, 6 coalesced nontemporal stores.
//     (R3 compile fix: nontemporal builtin needs native clang vector type,
//      not HIP_vector_type<float,4> -> use ext_vector_type(4).)

typedef float f32x4 __attribute__((ext_vector_type(4)));

#define KTORSO_H    0.42999f
#define KSHOULDER_W 0.3107f
#define KUPPER_ARM  0.19886f
#define KFOREARM    0.3f

__device__ __forceinline__ void kin1(float pitch, float roll, float yaw, float elbow,
                                     float& ox, float& oy, float& oz) {
    float sp, cp, sr, cr, sy, cy, se, ce;
    __sincosf(pitch, &sp, &cp);
    __sincosf(roll,  &sr, &cr);
    __sincosf(yaw,   &sy, &cy);
    __sincosf(elbow, &se, &ce);

    float a1x = cp * cy + sp * sr * sy;
    float a1y = cr * sy;
    float a1z = -sp * cy + cp * sr * sy;

    float a3x = sp * cr;
    float a3y = -sr;
    float a3z = cp * cr;

    float k3 = -KUPPER_ARM - KFOREARM * ce;   // coefficient on col3
    float k1 = -KFOREARM * se;                // coefficient on col1

    ox = k3 * a3x + k1 * a1x;                 // offset.x = 0
    oy = KSHOULDER_W + k3 * a3y + k1 * a1y;
    oz = KTORSO_H    + k3 * a3z + k1 * a1z;
}

__device__ __forceinline__ void kin4(const f32x4& p, const f32x4& r,
                                     const f32x4& y, const f32x4& e,
                                     f32x4* dst) {  // dst[0..2]
    float o[12];
    kin1(p.x, r.x, y.x, e.x, o[0], o[1], o[2]);
    kin1(p.y, r.y, y.y, e.y, o[3], o[4], o[5]);
    kin1(p.z, r.z, y.z, e.z, o[6], o[7], o[8]);
    kin1(p.w, r.w, y.w, e.w, o[9], o[10], o[11]);
    dst[0] = (f32x4){o[0], o[1], o[2], o[3]};
    dst[1] = (f32x4){o[4], o[5], o[6], o[7]};
    dst[2] = (f32x4){o[8], o[9], o[10], o[11]};
}

__global__ __launch_bounds__(256) void h1_kin_kernel(
    const f32x4* __restrict__ qp4,
    const f32x4* __restrict__ qr4,
    const f32x4* __restrict__ qy4,
    const f32x4* __restrict__ qe4,
    f32x4* __restrict__ out4,
    int n4)  // n4 = B/4
{
    __shared__ f32x4 lds4[1536];  // 256 threads * 6 float4 = 24 KB

    int t = threadIdx.x;
    long blk = (long)blockIdx.x * 512;      // this block's float4-input span
    int iA = (int)blk + t;                  // sweep A
    int iB = iA + 256;                      // sweep B

    // Issue all 8 loads up front (deep VMEM queue).
    f32x4 pA = qp4[iA], pB = qp4[iB];
    f32x4 rA = qr4[iA], rB = qr4[iB];
    f32x4 yA = qy4[iA], yB = qy4[iB];
    f32x4 eA = qe4[iA], eB = qe4[iB];

    f32x4 dA[3], dB[3];
    kin4(pA, rA, yA, eA, dA);
    kin4(pB, rB, yB, eB, dB);

    // Stage. Phase A occupies lds4[0..768), phase B lds4[768..1536).
    // Write stride 48B/lane -> spreads across banks (min aliasing).
    #pragma unroll
    for (int k = 0; k < 3; ++k) {
        lds4[t * 3 + k]       = dA[k];
        lds4[768 + t * 3 + k] = dB[k];
    }

    __syncthreads();

    // Coalesced nontemporal stores: 6 x 1024B-contiguous wave instructions.
    long base = (long)blockIdx.x * 1536;
    #pragma unroll
    for (int k = 0; k < 6; ++k) {
        __builtin_nontemporal_store(lds4[k * 256 + t], &out4[base + k * 256 + t]);
    }
}

extern "C" void kernel_launch(void* const* d_in, const int* in_sizes, int n_in,
                              void* d_out, int out_size, void* d_ws, size_t ws_size,
                              hipStream_t stream) {
    const float* qp = (const float*)d_in[0];
    const float* qr = (const float*)d_in[1];
    const float* qy = (const float*)d_in[2];
    const float* qe = (const float*)d_in[3];
    float* out = (float*)d_out;

    int n = in_sizes[0];        // B = 2097152
    int n4 = n / 4;             // 524288 float4 per input
    int block = 256;
    int grid = n4 / (block * 2);  // 1024 blocks, 8 elements/thread

    h1_kin_kernel<<<grid, block, 0, stream>>>(
        (const f32x4*)qp, (const f32x4*)qr, (const f32x4*)qy, (const f32x4*)qe,
        (f32x4*)out, n4);
}